// Round 11
// baseline (209.000 us; speedup 1.0000x reference)
//
#include <hip/hip_runtime.h>
#include <hip/hip_fp16.h>

#define N_ITEMS 100000
#define HID 128
#define NNZ_T 1600000
#define PREPW_BLOCKS 64            // 16384 / 256
#define RP_BLOCKS 391              // ceil(100001/256)

typedef unsigned short ushort_t;
typedef unsigned int uint_t;
typedef short bf16x8 __attribute__((ext_vector_type(8)));
typedef float f32x4 __attribute__((ext_vector_type(4)));   // clang vector: OK for NT builtins

static __device__ __forceinline__ ushort_t f32_to_bf16(float f) {
    uint_t u = __float_as_uint(f);
    uint_t r = (u + 0x7FFFu + ((u >> 16) & 1u)) >> 16;   // RNE
    return (ushort_t)r;
}

// === prep: [0..PREPW_BLOCKS) W fp32->bf16 | [PREPW_BLOCKS..) row_ptr ===
__global__ void prep(const float* __restrict__ W, const int* __restrict__ rows,
                     ushort_t* __restrict__ Wb, int* __restrict__ row_ptr) {
    if (blockIdx.x < PREPW_BLOCKS) {
        int i = blockIdx.x * 256 + threadIdx.x;
        Wb[i] = f32_to_bf16(W[i]);
        return;
    }
    int r = (blockIdx.x - PREPW_BLOCKS) * 256 + threadIdx.x;
    if (r > N_ITEMS) return;
    int lo = 0, hi = NNZ_T;
    while (lo < hi) {                       // lower_bound(rows, r), rows sorted
        int mid = (lo + hi) >> 1;
        if (rows[mid] < r) lo = mid + 1; else hi = mid;
    }
    row_ptr[r] = lo;
}

// === S = X @ W^T + b via bf16 MFMA (swapped operands), stored as FP16 ===
// X loads NONTEMPORAL (read-once stream; don't evict Wb/S from L2).
__global__ __launch_bounds__(256) void gemm_mfma(
    const float* __restrict__ X, const ushort_t* __restrict__ Wb,
    const float* __restrict__ bias, ushort_t* __restrict__ S) {
    const int lane = threadIdx.x & 63;
    const int wave = threadIdx.x >> 6;
    const int m = lane & 15;
    const int q = lane >> 4;
    const int row0 = blockIdx.x * 64 + wave * 16;

    int arow = row0 + m;
    if (arow >= N_ITEMS) arow = N_ITEMS - 1;          // clamp (stores guarded)

    f32x4 acc[8] = {};

#pragma unroll
    for (int kb = 0; kb < 4; ++kb) {
        const int k0 = kb * 32 + q * 8;
        f32x4 a0 = __builtin_nontemporal_load((const f32x4*)&X[(size_t)arow * HID + k0]);
        f32x4 a1 = __builtin_nontemporal_load((const f32x4*)&X[(size_t)arow * HID + k0 + 4]);
        bf16x8 xf;
        xf[0] = (short)f32_to_bf16(a0[0]); xf[1] = (short)f32_to_bf16(a0[1]);
        xf[2] = (short)f32_to_bf16(a0[2]); xf[3] = (short)f32_to_bf16(a0[3]);
        xf[4] = (short)f32_to_bf16(a1[0]); xf[5] = (short)f32_to_bf16(a1[1]);
        xf[6] = (short)f32_to_bf16(a1[2]); xf[7] = (short)f32_to_bf16(a1[3]);
#pragma unroll
        for (int nt = 0; nt < 8; ++nt) {
            bf16x8 wf = *(const bf16x8*)&Wb[(size_t)(nt * 16 + m) * HID + k0];
            acc[nt] = __builtin_amdgcn_mfma_f32_16x16x32_bf16(wf, xf, acc[nt], 0, 0, 0);
        }
    }

    const int srow = row0 + m;
    const bool ok = srow < N_ITEMS;
#pragma unroll
    for (int nt = 0; nt < 8; ++nt) {
        const int c0 = nt * 16 + q * 4;               // 4 consecutive out cols
        float4 bv = *(const float4*)&bias[c0];
        ushort_t h0 = __half_as_ushort(__float2half(acc[nt][0] + bv.x));
        ushort_t h1 = __half_as_ushort(__float2half(acc[nt][1] + bv.y));
        ushort_t h2 = __half_as_ushort(__float2half(acc[nt][2] + bv.z));
        ushort_t h3 = __half_as_ushort(__float2half(acc[nt][3] + bv.w));
        uint2 pk;
        pk.x = (uint_t)h0 | ((uint_t)h1 << 16);
        pk.y = (uint_t)h2 | ((uint_t)h3 << 16);
        if (ok) *(uint2*)&S[(size_t)srow * HID + c0] = pk;   // S: keep cached (spmm reuses)
    }
}

// === out[row] = sum vals*S[cols] over CSR segment (S in fp16) ===
// Round-8 structure (one wave per row, shfl edge window, quad-gather 16B/lane,
// __hfma2 accumulate) + cache hygiene: edge stream loads and out stores are
// NONTEMPORAL so L2 stays dedicated to the S gather working set.
__global__ __launch_bounds__(256) void spmm_csr(
    const int* __restrict__ cols, const float* __restrict__ vals,
    const int* __restrict__ row_ptr, const ushort_t* __restrict__ S,
    float* __restrict__ out) {
    const int lane = threadIdx.x & 63;
    const int row = blockIdx.x * 4 + ((threadIdx.x >> 6) & 3);
    if (row >= N_ITEMS) return;

    const int g = lane >> 4;        // edge slot within a quad
    const int l = lane & 15;        // column octet: cols 8*l .. 8*l+7

    const int p0 = row_ptr[row];
    const int p1 = row_ptr[row + 1];

    __half2 acch[4];
    acch[0] = __float2half2_rn(0.f); acch[1] = __float2half2_rn(0.f);
    acch[2] = __float2half2_rn(0.f); acch[3] = __float2half2_rn(0.f);

    for (int w0 = p0; w0 < p1; w0 += 64) {
        const int nw = min(64, p1 - w0);
        // whole window's edge data in registers: 2 coalesced nt loads
        const int idx = w0 + lane;
        const int cidx = min(idx, p1 - 1);
        const int c_l = __builtin_nontemporal_load(&cols[cidx]);
        const float v_raw = __builtin_nontemporal_load(&vals[cidx]);
        const float v_l = (idx < p1) ? v_raw : 0.f;

        for (int s0 = 0; s0 < nw; s0 += 16) {
            uint4 u[4]; float v[4];
#pragma unroll
            for (int t = 0; t < 4; ++t) {             // 16 edges in flight
                const int slot = s0 + 4 * t + g;      // may pad past nw: v=0
                const int c = __shfl(c_l, slot, 64);
                v[t] = __shfl(v_l, slot, 64);
                u[t] = *(const uint4*)&S[(size_t)c * HID + 8 * l];
            }
#pragma unroll
            for (int t = 0; t < 4; ++t) {
                const __half2 vv = __float2half2_rn(v[t]);
                acch[0] = __hfma2(vv, *(const __half2*)&u[t].x, acch[0]);
                acch[1] = __hfma2(vv, *(const __half2*)&u[t].y, acch[1]);
                acch[2] = __hfma2(vv, *(const __half2*)&u[t].z, acch[2]);
                acch[3] = __hfma2(vv, *(const __half2*)&u[t].w, acch[3]);
            }
        }
    }

    // unpack to f32, reduce the 4 edge-groups (lanes l, l+16, l+32, l+48)
    float acc[8];
#pragma unroll
    for (int j = 0; j < 4; ++j) {
        acc[2 * j]     = __low2float(acch[j]);
        acc[2 * j + 1] = __high2float(acch[j]);
    }
#pragma unroll
    for (int e = 0; e < 8; ++e) {
        acc[e] += __shfl_xor(acc[e], 16, 64);
        acc[e] += __shfl_xor(acc[e], 32, 64);
    }
    if (g == 0) {
        float* p = &out[(size_t)row * HID + 8 * l];
        f32x4 o0 = { acc[0], acc[1], acc[2], acc[3] };
        f32x4 o1 = { acc[4], acc[5], acc[6], acc[7] };
        __builtin_nontemporal_store(o0, (f32x4*)p);
        __builtin_nontemporal_store(o1, (f32x4*)(p + 4));
    }
}

extern "C" void kernel_launch(void* const* d_in, const int* in_sizes, int n_in,
                              void* d_out, int out_size, void* d_ws, size_t ws_size,
                              hipStream_t stream) {
    const float* X    = (const float*)d_in[0];
    const int*   rows = (const int*)  d_in[1];
    const int*   cols = (const int*)  d_in[2];
    const float* vals = (const float*)d_in[3];
    const float* W    = (const float*)d_in[4];
    const float* bias = (const float*)d_in[5];
    float* out = (float*)d_out;

    ushort_t* Wb      = (ushort_t*)d_ws;                    // 32 KB (bf16)
    ushort_t* S       = Wb + HID * HID;                     // 25.6 MB (fp16)
    int*      row_ptr = (int*)(S + (size_t)N_ITEMS * HID);  // 400 KB

    prep<<<PREPW_BLOCKS + RP_BLOCKS, 256, 0, stream>>>(W, rows, Wb, row_ptr);
    gemm_mfma<<<(N_ITEMS + 63) / 64, 256, 0, stream>>>(X, Wb, bias, S);
    spmm_csr<<<(N_ITEMS + 3) / 4, 256, 0, stream>>>(cols, vals, row_ptr, S, out);
}